// Round 1
// 99.394 us; speedup vs baseline: 1.0143x; 1.0143x over previous
//
#include <hip/hip_runtime.h>
#include <math.h>

#define NB 256     // N nodes
#define CH 64      // C input features
#define OUTF 64    // O output features
#define GK 8       // GRID_SIZE + SPLINE_ORDER
#define UIN 128    // update-KAN input dim (C + O)
#define KM (CH * 9)    // 576 feature rows for msg KAN (8 spline + 1 silu per ch)
#define KM4 (KM / 4)   // 144
#define KU (UIN * 9)   // 1152 feature rows for update KAN
#define KU4 (KU / 4)   // 288

// workspace layout in floats (xT eliminated this round)
#define WS_MSG 0                     // 512*64            = 32768
#define WS_W2M 32768                 // 144*64*4          = 36864
#define WS_W2U 69632                 // 288*64*4          = 73728
// total 143360 floats = 560 KB

__device__ __forceinline__ float silu(float v) {
    return v * __builtin_amdgcn_rcpf(1.0f + __expf(-v));
}

// Uniform cubic B-spline, knots t(m)=0.4m-2.2. Interval d=floor((r+2.2)*2.5),
// u=frac. 4 nonzero bases m=d-3..d with segment polys
// {(1-u)^3, 3u^3-6u^2+4, -3u^3+3u^2+3u+1, u^3}/6. Out of grid -> d=11 (zeros).
__device__ __forceinline__ void spline4(float r, int& d, float4& v) {
    float p = fmaf(r, 2.5f, 5.5f);   // (r+2.2)*2.5
    float fd = floorf(p);
    d = (int)fd;
    float u = p - fd;
    if ((unsigned)d > 10u) d = 11;
    float um = 1.0f - u;
    float u2 = u * u, u3 = u2 * u;
    const float k6 = 1.0f / 6.0f;
    v.x = um * um * um * k6;
    v.y = (3.0f * u3 - 6.0f * u2 + 4.0f) * k6;
    v.z = (-3.0f * u3 + 3.0f * u2 + 3.0f * u + 1.0f) * k6;
    v.w = u3 * k6;
}

// Weight-table prep only (xT removed): folded/transposed W2m + W2u.
__global__ __launch_bounds__(256) void prep_kernel(
    const float* __restrict__ mwb, const float* __restrict__ mws,
    const float* __restrict__ mwsc,
    const float* __restrict__ uwb, const float* __restrict__ uws,
    const float* __restrict__ uwsc,
    float* __restrict__ ws) {
    int t = blockIdx.x * 256 + threadIdx.x;
    if (t < KM4 * OUTF) {                        // W2m[k4][o] float4 over k
        int k4 = t >> 6, o = t & 63;
        float4 v;
#pragma unroll
        for (int kk = 0; kk < 4; ++kk) {
            int k = k4 * 4 + kk, c = k / 9, g = k - c * 9;
            ((float*)&v)[kk] = (g < 8)
                ? mws[(o * CH + c) * GK + g] * mwsc[o * CH + c]
                : mwb[o * CH + c];
        }
        ((float4*)(ws + WS_W2M))[t] = v;
        return;
    }
    int t2 = t - KM4 * OUTF;
    if (t2 < KU4 * OUTF) {                       // W2u[k4][o] float4 over k
        int k4 = t2 >> 6, o = t2 & 63;
        float4 v;
#pragma unroll
        for (int kk = 0; kk < 4; ++kk) {
            int k = k4 * 4 + kk, c = k / 9, g = k - c * 9;
            ((float*)&v)[kk] = (g < 8)
                ? uws[(o * UIN + c) * GK + g] * uwsc[o * UIN + c]
                : uwb[o * UIN + c];
        }
        ((float4*)(ws + WS_W2U))[t2] = v;
    }
}

// msg[row,o]: features in LDS, then 4 waves x 36 float4-k iters, coalesced W.
__global__ __launch_bounds__(256) void msg_kernel(
    const float* __restrict__ x, const float* __restrict__ w2m,
    float* __restrict__ msg) {
    const int row = blockIdx.x, tid = threadIdx.x;
    __shared__ __align__(16) float F[KM];
    __shared__ float part[4][OUTF];

    if (tid < CH) {
        float v = x[row * CH + tid];
#pragma unroll
        for (int g = 0; g < 8; ++g) F[tid * 9 + g] = 0.0f;
        F[tid * 9 + 8] = silu(v);
        int d; float4 vv; spline4(v, d, vv);
#pragma unroll
        for (int k = 0; k < 4; ++k) {
            int m = d - 3 + k;
            if ((unsigned)m < 8u) F[tid * 9 + m] = ((const float*)&vv)[k];
        }
    }
    __syncthreads();

    const int o = tid & 63, w = tid >> 6;
    const float4* W = (const float4*)w2m;
    const float4* Fv = (const float4*)F;
    float acc = 0.0f;
#pragma unroll 4
    for (int k4 = w * 36; k4 < w * 36 + 36; ++k4) {
        float4 f = Fv[k4];                 // uniform LDS b128 broadcast
        float4 wt = W[k4 * 64 + o];        // coalesced 1KB/wave
        acc += f.x * wt.x + f.y * wt.y + f.z * wt.z + f.w * wt.w;
    }
    part[w][o] = acc;
    __syncthreads();
    if (tid < OUTF)
        msg[row * OUTF + tid] =
            part[0][tid] + part[1][tid] + part[2][tid] + part[3][tid];
}

// One block per (b,i): energy -> softmax -> aggregate -> update KAN.
__global__ __launch_bounds__(256, 2) void gat_kernel(
    const float* __restrict__ x,     // (B, N, C)
    const int* __restrict__ adj,
    const float* __restrict__ fwb, const float* __restrict__ fws,
    const float* __restrict__ fwsc,
    const float* __restrict__ w2u,   // (KU4*64) float4
    const float* __restrict__ msg,   // (B, N, O)
    float* __restrict__ out) {
    const int b = blockIdx.x >> 8;
    const int i = blockIdx.x & 255;
    const int tid = threadIdx.x;     // == j in energy phase

    __shared__ float4 cpad[CH][16];  // per-interval cubic coefs (zero-padded)
    __shared__ float4 xi4[16];       // x_i row as float4
    __shared__ float4 fb4[16];       // fwb as float4
    __shared__ float alpha[NB];
    __shared__ float comb[UIN];
    __shared__ __align__(16) float Fu[KU];
    __shared__ float4 part4[16][16]; // aggr partials: 16 segs x 64 floats
    __shared__ float part[4][OUTF];  // matvec partials
    __shared__ float wred[4];

    // Register-preload this thread's j-row of x (j = tid); issues 16 b128
    // loads whose latency hides under the cpad/LDS setup below.
    float4 xj[16];
    {
        const float4* xrow = (const float4*)(x + (b * NB + tid) * CH);
#pragma unroll
        for (int c4 = 0; c4 < 16; ++c4) xj[c4] = xrow[c4];
    }

    if (tid < 16) {
        float4 v = ((const float4*)(x + (b * NB + i) * CH))[tid];
        xi4[tid] = v;
        fb4[tid] = ((const float4*)fwb)[tid];
        ((float4*)comb)[tid] = v;
    }
    // cubic coefficient table: s(u) = a0 + u(a1 + u(a2 + u a3)) on interval d
#pragma unroll
    for (int e = tid; e < CH * 16; e += 256) {
        int c = e >> 4, dd = e & 15;
        float4 cf = make_float4(0.f, 0.f, 0.f, 0.f);
        if (dd <= 10) {
            float sc = fwsc[c];
            float w0 = 0.f, w1 = 0.f, w2 = 0.f, w3 = 0.f;
            int m0 = dd - 3;
            if ((unsigned)(m0 + 0) < 8u) w0 = fws[c * GK + m0 + 0] * sc;
            if ((unsigned)(m0 + 1) < 8u) w1 = fws[c * GK + m0 + 1] * sc;
            if ((unsigned)(m0 + 2) < 8u) w2 = fws[c * GK + m0 + 2] * sc;
            if ((unsigned)(m0 + 3) < 8u) w3 = fws[c * GK + m0 + 3] * sc;
            cf.x = (w0 + 4.0f * w1 + w2) * (1.0f / 6.0f);
            cf.y = (w2 - w0) * 0.5f;
            cf.z = (w0 - 2.0f * w1 + w2) * 0.5f;
            cf.w = (w3 - w0 + 3.0f * (w1 - w2)) * (1.0f / 6.0f);
        }
        cpad[c][dd] = cf;
    }
    __syncthreads();

    // ---- energy(i, j=tid): x-row in registers + LDS b128 coef gather ----
    float e = 0.0f;
#pragma unroll
    for (int c4 = 0; c4 < 16; ++c4) {
        float4 xiv = xi4[c4];              // uniform b128 broadcast
        float4 fbv = fb4[c4];
        float4 xjv = xj[c4];               // registers
#pragma unroll
        for (int q = 0; q < 4; ++q) {
            float r = ((const float*)&xiv)[q] - ((const float*)&xjv)[q];
            float pp = fmaf(r, 2.5f, 5.5f);
            float fd = floorf(pp);
            int d = (int)fd;
            float u = pp - fd;
            if ((unsigned)d > 10u) d = 11;
            float4 cf = cpad[c4 * 4 + q][d];   // b128 gather
            float t = fmaf(u, cf.w, cf.z);
            t = fmaf(u, t, cf.y);
            t = fmaf(u, t, cf.x);
            e += fmaf(silu(r), ((const float*)&fbv)[q], t);
        }
    }
    if (adj[(b * NB + i) * NB + tid] == 0) e = -1e9f;

    // ---- softmax over j ----
    float mx = e;
#pragma unroll
    for (int off = 32; off > 0; off >>= 1)
        mx = fmaxf(mx, __shfl_xor(mx, off, 64));
    if ((tid & 63) == 0) wred[tid >> 6] = mx;
    __syncthreads();
    mx = fmaxf(fmaxf(wred[0], wred[1]), fmaxf(wred[2], wred[3]));
    float pexp = __expf(e - mx);
    float sw = pexp;
#pragma unroll
    for (int off = 32; off > 0; off >>= 1)
        sw += __shfl_xor(sw, off, 64);
    __syncthreads();
    if ((tid & 63) == 0) wred[tid >> 6] = sw;
    __syncthreads();
    float denom = wred[0] + wred[1] + wred[2] + wred[3];
    alpha[tid] = pexp * __builtin_amdgcn_rcpf(denom);
    __syncthreads();

    // ---- aggr[o] = sum_j alpha[j]*msg[b,j,o], float4 over o ----
    {
        const int o4 = tid & 15, seg = tid >> 4;   // 16 segs x 16 j each
        const float4* msgb4 = (const float4*)(msg + (b * NB + seg * 16) * OUTF);
        float4 a = make_float4(0.f, 0.f, 0.f, 0.f);
#pragma unroll
        for (int jj = 0; jj < 16; ++jj) {
            float al = alpha[seg * 16 + jj];
            float4 mv = msgb4[jj * 16 + o4];       // coalesced b128
            a.x = fmaf(al, mv.x, a.x);
            a.y = fmaf(al, mv.y, a.y);
            a.z = fmaf(al, mv.z, a.z);
            a.w = fmaf(al, mv.w, a.w);
        }
        part4[seg][o4] = a;
    }
    __syncthreads();
    if (tid < OUTF) {
        const float* p = (const float*)part4;
        float s = 0.0f;
#pragma unroll
        for (int sg = 0; sg < 16; ++sg) s += p[sg * 64 + tid];  // conflict-free
        comb[CH + tid] = s;
    }
    __syncthreads();

    // ---- update-KAN features (128 channels -> 1152 LDS rows) ----
    if (tid < UIN) {
        float v = comb[tid];
#pragma unroll
        for (int g = 0; g < 8; ++g) Fu[tid * 9 + g] = 0.0f;
        Fu[tid * 9 + 8] = silu(v);
        int d; float4 vv; spline4(v, d, vv);
#pragma unroll
        for (int k = 0; k < 4; ++k) {
            int m = d - 3 + k;
            if ((unsigned)m < 8u) Fu[tid * 9 + m] = ((const float*)&vv)[k];
        }
    }
    __syncthreads();

    // ---- update matvec: 4 waves x 72 float4-k iters, coalesced W ----
    {
        const int o = tid & 63, w = tid >> 6;
        const float4* W = (const float4*)w2u;
        const float4* Fv = (const float4*)Fu;
        float acc = 0.0f;
#pragma unroll 4
        for (int k4 = w * 72; k4 < w * 72 + 72; ++k4) {
            float4 f = Fv[k4];
            float4 wt = W[k4 * 64 + o];
            acc += f.x * wt.x + f.y * wt.y + f.z * wt.z + f.w * wt.w;
        }
        part[w][o] = acc;
    }
    __syncthreads();
    if (tid < OUTF)
        out[(b * NB + i) * OUTF + tid] =
            part[0][tid] + part[1][tid] + part[2][tid] + part[3][tid];
}

extern "C" void kernel_launch(void* const* d_in, const int* in_sizes, int n_in,
                              void* d_out, int out_size, void* d_ws, size_t ws_size,
                              hipStream_t stream) {
    const float* x     = (const float*)d_in[0];
    const int*   adj   = (const int*)d_in[1];
    const float* fwb   = (const float*)d_in[2];
    const float* fws   = (const float*)d_in[3];
    const float* fwsc  = (const float*)d_in[4];
    const float* mwb   = (const float*)d_in[5];
    const float* mws   = (const float*)d_in[6];
    const float* mwsc  = (const float*)d_in[7];
    const float* uwb   = (const float*)d_in[8];
    const float* uws   = (const float*)d_in[9];
    const float* uwsc  = (const float*)d_in[10];
    float* out = (float*)d_out;
    float* ws = (float*)d_ws;

    const int BN = in_sizes[0] / CH;   // 512

    const int prep_threads = KM4 * OUTF + KU4 * OUTF; // 27648
    prep_kernel<<<(prep_threads + 255) / 256, 256, 0, stream>>>(
        mwb, mws, mwsc, uwb, uws, uwsc, ws);
    msg_kernel<<<BN, 256, 0, stream>>>(x, ws + WS_W2M, ws + WS_MSG);
    gat_kernel<<<BN, 256, 0, stream>>>(x, adj, fwb, fws, fwsc,
                                       ws + WS_W2U, ws + WS_MSG, out);
}